// Round 4
// baseline (39235.797 us; speedup 1.0000x reference)
//
#include <hip/hip_runtime.h>

#define S_LEN 4096
#define BATCH 16
#define HID   256     // H == F == 256
#define GATE4 1024    // 4F

typedef __bf16 bf16x8 __attribute__((ext_vector_type(8)));
typedef float  f32x4  __attribute__((ext_vector_type(4)));

union FragU {
    unsigned short u[8];
    bf16x8 v;
    uint4  q;
};

__device__ __forceinline__ unsigned short f2bf(float f) {
    unsigned u = __builtin_bit_cast(unsigned, f);
    u += 0x7fffu + ((u >> 16) & 1u);
    return (unsigned short)(u >> 16);
}
__device__ __forceinline__ float bf2f(unsigned short s) {
    unsigned u = ((unsigned)s) << 16;
    return __builtin_bit_cast(float, u);
}
__device__ __forceinline__ float sigmoid_f(float x) {
    return 1.f / (1.f + __expf(-x));
}
__device__ __forceinline__ float tanh_f(float x) {
    float e = __expf(2.f * x);
    return 1.f - 2.f / (e + 1.f);
}

// ---------------------------------------------------------------------------
// Kernel 1: xp[d][s][b][colp] = (x @ Wi_d + b_d), bf16, PAIR-SWIZZLED layout:
// for dir-local gate column ncol = g*256 + f, storage column is
//   colp = g*256 + (f & ~31) + ((f & 15) << 1) + ((f >> 4) & 1)
// so that the recurrence lane owning (f, f+16) reads both as ONE dword.
// ---------------------------------------------------------------------------
__global__ __launch_bounds__(256, 2) void xp_gemm(
    const float* __restrict__ X,
    const float* __restrict__ Wi_fw, const float* __restrict__ b_fw,
    const float* __restrict__ Wi_rv, const float* __restrict__ b_rv,
    unsigned short* __restrict__ xp_fw, unsigned short* __restrict__ xp_rv)
{
    const int dir = blockIdx.z;
    const float* Wi   = dir ? Wi_rv : Wi_fw;
    const float* bias = dir ? b_rv  : b_fw;
    unsigned short* xp = dir ? xp_rv : xp_fw;

    __shared__ unsigned short As[64][40];
    __shared__ unsigned short Bs[64][40];

    const int tid  = threadIdx.x;
    const int lane = tid & 63;
    const int wid  = tid >> 6;
    const int quad = lane >> 4;
    const int l16  = lane & 15;
    const int wm = wid >> 1, wn = wid & 1;

    const int r0 = blockIdx.x * 64;
    const int n0 = blockIdx.y * 64;

    const int ai = tid & 63;
    const int ak = (tid >> 6) * 8;
    const int bk = tid >> 3;
    const int bj = (tid & 7) * 8;

    const int r  = r0 + ai;
    const int t  = r >> 4, bb = r & 15;
    const int t_eff = dir ? (S_LEN - 1 - t) : t;
    const float* Arow = X + ((size_t)bb * S_LEN + t_eff) * HID;

    f32x4 acc[2][2];
    #pragma unroll
    for (int i = 0; i < 2; ++i)
        #pragma unroll
        for (int j = 0; j < 2; ++j) { acc[i][j][0]=0.f; acc[i][j][1]=0.f; acc[i][j][2]=0.f; acc[i][j][3]=0.f; }

    for (int kb = 0; kb < HID / 32; ++kb) {
        {
            const float* p = Arow + kb * 32 + ak;
            float4 v0 = *(const float4*)p;
            float4 v1 = *(const float4*)(p + 4);
            FragU fu;
            fu.u[0]=f2bf(v0.x); fu.u[1]=f2bf(v0.y); fu.u[2]=f2bf(v0.z); fu.u[3]=f2bf(v0.w);
            fu.u[4]=f2bf(v1.x); fu.u[5]=f2bf(v1.y); fu.u[6]=f2bf(v1.z); fu.u[7]=f2bf(v1.w);
            *(uint4*)&As[ai][ak] = fu.q;
        }
        {
            const float* p = Wi + (size_t)(kb * 32 + bk) * GATE4 + n0 + bj;
            float4 v0 = *(const float4*)p;
            float4 v1 = *(const float4*)(p + 4);
            unsigned short tmp[8] = { f2bf(v0.x), f2bf(v0.y), f2bf(v0.z), f2bf(v0.w),
                                      f2bf(v1.x), f2bf(v1.y), f2bf(v1.z), f2bf(v1.w) };
            #pragma unroll
            for (int jj = 0; jj < 8; ++jj) Bs[bj + jj][bk] = tmp[jj];
        }
        __syncthreads();

        bf16x8 a0 = *(const bf16x8*)&As[wm * 32 + l16][quad * 8];
        bf16x8 a1 = *(const bf16x8*)&As[wm * 32 + 16 + l16][quad * 8];
        bf16x8 B0 = *(const bf16x8*)&Bs[wn * 32 + l16][quad * 8];
        bf16x8 B1 = *(const bf16x8*)&Bs[wn * 32 + 16 + l16][quad * 8];
        acc[0][0] = __builtin_amdgcn_mfma_f32_16x16x32_bf16(a0, B0, acc[0][0], 0, 0, 0);
        acc[0][1] = __builtin_amdgcn_mfma_f32_16x16x32_bf16(a0, B1, acc[0][1], 0, 0, 0);
        acc[1][0] = __builtin_amdgcn_mfma_f32_16x16x32_bf16(a1, B0, acc[1][0], 0, 0, 0);
        acc[1][1] = __builtin_amdgcn_mfma_f32_16x16x32_bf16(a1, B1, acc[1][1], 0, 0, 0);
        __syncthreads();
    }

    #pragma unroll
    for (int am = 0; am < 2; ++am)
        #pragma unroll
        for (int bn = 0; bn < 2; ++bn) {
            int ncol = n0 + wn * 32 + bn * 16 + l16;
            int f    = ncol & 255;
            int g    = ncol >> 8;
            int colp = g * 256 + (f & ~31) + ((f & 15) << 1) + ((f >> 4) & 1);
            float bv = bias[ncol];
            #pragma unroll
            for (int rr = 0; rr < 4; ++rr) {
                int rrow = r0 + wm * 32 + am * 16 + quad * 4 + rr;
                float v = acc[am][bn][rr] + bv;
                xp[(size_t)rrow * GATE4 + colp] = f2bf(v);
            }
        }
}

// ---------------------------------------------------------------------------
// Kernel 2: recurrence. ONE workgroup per direction (grid=2), 512 threads =
// 8 waves, wave wid owns f in [wid*32, wid*32+32) for all 4 gates. ALL of Wh
// lives in registers: Bfrag[4][2][8] = 256 VGPRs/lane. __launch_bounds__(512,1)
// gives the allocator the full 512-reg/wave budget (round-1 failed because
// (512,2) capped it at 256 and spilled Bfrag to scratch). Double-buffered
// LDS h, one lgkmcnt-only s_barrier per step, xp prefetched 2 steps ahead.
// ---------------------------------------------------------------------------
__global__ __launch_bounds__(512, 1) void lstm_rec(
    const float* __restrict__ Wh_fw, const float* __restrict__ Wh_rv,
    const unsigned short* __restrict__ xp_fw, const unsigned short* __restrict__ xp_rv,
    float* __restrict__ out,            // [B][S][512]
    float* __restrict__ finals)         // c_fw,h_fw,c_rv,h_rv (each 16x256)
{
    const int dir = blockIdx.x;         // 0..1
    const float* Wh = dir ? Wh_rv : Wh_fw;
    const unsigned short* xp = dir ? xp_rv : xp_fw;

    const int tid  = threadIdx.x;
    const int lane = tid & 63;
    const int wid  = tid >> 6;          // 0..7
    const int quad = lane >> 4;
    const int l16  = lane & 15;

    const int fbase = wid * 32;         // dir-local f block of this wave

    __shared__ unsigned short hbuf[2][16][264];   // double-buffered h (bf16)

    for (int i = tid; i < 16 * 264; i += 512) (&hbuf[0][0][0])[i] = 0;

    // Wh -> B-fragments (one-time): lane holds
    // Wh[k = kt*32 + quad*8 + j][g*256 + fbase + n*16 + l16], j=0..7.
    bf16x8 Bfrag[4][2][8];
    #pragma unroll
    for (int g = 0; g < 4; ++g)
        #pragma unroll
        for (int n = 0; n < 2; ++n) {
            const int col = g * 256 + fbase + n * 16 + l16;
            #pragma unroll
            for (int kt = 0; kt < 8; ++kt) {
                FragU fu;
                #pragma unroll
                for (int j = 0; j < 8; ++j) {
                    int k = kt * 32 + quad * 8 + j;
                    fu.u[j] = f2bf(Wh[(size_t)k * GATE4 + col]);
                }
                Bfrag[g][n][kt] = fu.v;
            }
        }

    float cst[2][4]  = {};
    float hval[2][4] = {};

    // xp dword base (pair-swizzled layout): lane reads (f, f+16) as one uint
    // at uint-index ubase + rr*512 + g*128 within a step's [16][1024] block.
    const size_t ubase = (size_t)quad * 2048 + wid * 16 + l16;

    unsigned int xpA[4][4], xpB[4][4];   // [g][rr] packed pairs, steps s/s+1
    {
        const unsigned int* x0 = (const unsigned int*)xp + ubase;
        const unsigned int* x1 = (const unsigned int*)(xp + (size_t)BATCH * GATE4) + ubase;
        #pragma unroll
        for (int g = 0; g < 4; ++g)
            #pragma unroll
            for (int rr = 0; rr < 4; ++rr) {
                xpA[g][rr] = x0[rr * 512 + g * 128];
                xpB[g][rr] = x1[rr * 512 + g * 128];
            }
    }

    __syncthreads();   // hbuf[0] zeroed (also drains init loads; one-time)

    int p = 0;
    auto step = [&](int s, unsigned int (&xpc)[4][4]) {
        // A-fragments from h in LDS
        bf16x8 Afrag[8];
        #pragma unroll
        for (int kt = 0; kt < 8; ++kt)
            Afrag[kt] = *(const bf16x8*)&hbuf[p][l16][kt * 32 + quad * 8];

        f32x4 accg[4][2];
        #pragma unroll
        for (int g = 0; g < 4; ++g)
            #pragma unroll
            for (int n = 0; n < 2; ++n) {
                accg[g][n][0]=0.f; accg[g][n][1]=0.f; accg[g][n][2]=0.f; accg[g][n][3]=0.f;
            }

        #pragma unroll
        for (int kt = 0; kt < 8; ++kt)
            #pragma unroll
            for (int g = 0; g < 4; ++g) {
                accg[g][0] = __builtin_amdgcn_mfma_f32_16x16x32_bf16(Afrag[kt], Bfrag[g][0][kt], accg[g][0], 0, 0, 0);
                accg[g][1] = __builtin_amdgcn_mfma_f32_16x16x32_bf16(Afrag[kt], Bfrag[g][1][kt], accg[g][1], 0, 0, 0);
            }

        // gates: lane owns (m = quad*4+rr, f = fbase + n*16 + l16)
        unsigned short hb[2][4];
        #pragma unroll
        for (int n = 0; n < 2; ++n)
            #pragma unroll
            for (int rr = 0; rr < 4; ++rr) {
                unsigned wz0 = xpc[0][rr], wz1 = xpc[1][rr];
                unsigned wz2 = xpc[2][rr], wz3 = xpc[3][rr];
                float zi = accg[0][n][rr] + bf2f((unsigned short)(n ? (wz0 >> 16) : wz0));
                float zf = accg[1][n][rr] + bf2f((unsigned short)(n ? (wz1 >> 16) : wz1));
                float zg = accg[2][n][rr] + bf2f((unsigned short)(n ? (wz2 >> 16) : wz2));
                float zo = accg[3][n][rr] + bf2f((unsigned short)(n ? (wz3 >> 16) : wz3));
                float ig = sigmoid_f(zi);
                float fg = sigmoid_f(zf);
                float gg = tanh_f(zg);
                float og = sigmoid_f(zo);
                float c  = fg * cst[n][rr] + ig * gg;
                cst[n][rr]  = c;
                float h  = og * tanh_f(c);
                hval[n][rr] = h;
                hb[n][rr]   = f2bf(h);
            }

        // refetch xp for s+2 into this register set (in flight across barrier)
        if (s + 2 < S_LEN) {
            const unsigned int* xr =
                (const unsigned int*)(xp + (size_t)(s + 2) * (BATCH * GATE4)) + ubase;
            #pragma unroll
            for (int g = 0; g < 4; ++g)
                #pragma unroll
                for (int rr = 0; rr < 4; ++rr)
                    xpc[g][rr] = xr[rr * 512 + g * 128];
        }

        // new h -> other LDS buffer
        #pragma unroll
        for (int n = 0; n < 2; ++n)
            #pragma unroll
            for (int rr = 0; rr < 4; ++rr)
                hbuf[p ^ 1][quad * 4 + rr][fbase + n * 16 + l16] = hb[n][rr];

        // fp32 output (fire-and-forget global stores; never vmcnt-drained)
        {
            const int t_orig = dir ? (S_LEN - 1 - s) : s;
            float* ob = out + (size_t)t_orig * 512 + dir * 256 + fbase + l16;
            #pragma unroll
            for (int n = 0; n < 2; ++n)
                #pragma unroll
                for (int rr = 0; rr < 4; ++rr)
                    ob[(size_t)(quad * 4 + rr) * S_LEN * 512 + n * 16] = hval[n][rr];
        }

        // producer barrier: LDS ops must land; global loads/stores stay in
        // flight (lgkmcnt only — NOT __syncthreads()).
        asm volatile("s_waitcnt lgkmcnt(0)" ::: "memory");
        __builtin_amdgcn_s_barrier();
        p ^= 1;
    };

    for (int s2 = 0; s2 < S_LEN; s2 += 2) {
        step(s2,     xpA);
        step(s2 + 1, xpB);
    }

    // final states: c then h, fw block then rv block
    {
        float* cdst = finals + (dir ? 8192 : 0);
        float* hdst = cdst + 4096;
        #pragma unroll
        for (int n = 0; n < 2; ++n)
            #pragma unroll
            for (int rr = 0; rr < 4; ++rr) {
                int m = quad * 4 + rr;
                int f = fbase + n * 16 + l16;
                cdst[m * 256 + f] = cst[n][rr];
                hdst[m * 256 + f] = hval[n][rr];
            }
    }
}

// ---------------------------------------------------------------------------
extern "C" void kernel_launch(void* const* d_in, const int* in_sizes, int n_in,
                              void* d_out, int out_size, void* d_ws, size_t ws_size,
                              hipStream_t stream)
{
    const float* X     = (const float*)d_in[0];
    const float* Wi_fw = (const float*)d_in[1];
    const float* Wh_fw = (const float*)d_in[2];
    const float* b_fw  = (const float*)d_in[3];
    const float* Wi_rv = (const float*)d_in[4];
    const float* Wh_rv = (const float*)d_in[5];
    const float* b_rv  = (const float*)d_in[6];

    float* out    = (float*)d_out;
    float* finals = out + (size_t)BATCH * S_LEN * 512;

    char* ws = (char*)d_ws;
    unsigned short* xp_fw = (unsigned short*)ws;                          // 128 MiB
    unsigned short* xp_rv = (unsigned short*)(ws + 134217728ull);         // 128 MiB

    dim3 g(65536 / 64, 1024 / 64, 2);
    xp_gemm<<<g, 256, 0, stream>>>(X, Wi_fw, b_fw, Wi_rv, b_rv, xp_fw, xp_rv);

    lstm_rec<<<2, 512, 0, stream>>>(Wh_fw, Wh_rv, xp_fw, xp_rv, out, finals);
}

// Round 6
// 12020.911 us; speedup vs baseline: 3.2640x; 3.2640x over previous
//
#include <hip/hip_runtime.h>

#define S_LEN 4096
#define BATCH 16
#define HID   256     // H == F == 256
#define GATE4 1024    // 4F

typedef __bf16 bf16x8 __attribute__((ext_vector_type(8)));
typedef float  f32x4  __attribute__((ext_vector_type(4)));

union FragU {
    unsigned short u[8];
    bf16x8 v;
    uint4  q;
};

__device__ __forceinline__ unsigned short f2bf(float f) {
    unsigned u = __builtin_bit_cast(unsigned, f);
    u += 0x7fffu + ((u >> 16) & 1u);
    return (unsigned short)(u >> 16);
}
__device__ __forceinline__ float bf2f(unsigned short s) {
    unsigned u = ((unsigned)s) << 16;
    return __builtin_bit_cast(float, u);
}
__device__ __forceinline__ float sigmoid_f(float x) {
    return 1.f / (1.f + __expf(-x));
}
__device__ __forceinline__ float tanh_f(float x) {
    float e = __expf(2.f * x);
    return 1.f - 2.f / (e + 1.f);
}

// ---------------------------------------------------------------------------
// Kernel 0: init. ctrl[8..15]=per-XCD claim counters, ctrl[16]=winner XCD.
// exch (64 KiB) zeroed so poisoned tags can never match a live step tag.
// ---------------------------------------------------------------------------
__global__ void init_ctrl(unsigned int* ctrl, unsigned int* exch4) {
    int t = threadIdx.x;
    if (t < 128) ctrl[t] = (t == 16) ? 0xFFFFFFFFu : 0u;
    for (int i = t; i < 16384; i += 1024) exch4[i] = 0u;
}

// ---------------------------------------------------------------------------
// Kernel 1: xp gemm (unchanged from the proven round-3 version)
// ---------------------------------------------------------------------------
__global__ __launch_bounds__(256, 2) void xp_gemm(
    const float* __restrict__ X,
    const float* __restrict__ Wi_fw, const float* __restrict__ b_fw,
    const float* __restrict__ Wi_rv, const float* __restrict__ b_rv,
    unsigned short* __restrict__ xp_fw, unsigned short* __restrict__ xp_rv)
{
    const int dir = blockIdx.z;
    const float* Wi   = dir ? Wi_rv : Wi_fw;
    const float* bias = dir ? b_rv  : b_fw;
    unsigned short* xp = dir ? xp_rv : xp_fw;

    __shared__ unsigned short As[64][40];
    __shared__ unsigned short Bs[64][40];

    const int tid  = threadIdx.x;
    const int lane = tid & 63;
    const int wid  = tid >> 6;
    const int quad = lane >> 4;
    const int l16  = lane & 15;
    const int wm = wid >> 1, wn = wid & 1;

    const int r0 = blockIdx.x * 64;
    const int n0 = blockIdx.y * 64;

    const int ai = tid & 63;
    const int ak = (tid >> 6) * 8;
    const int bk = tid >> 3;
    const int bj = (tid & 7) * 8;

    const int r  = r0 + ai;
    const int t  = r >> 4, bb = r & 15;
    const int t_eff = dir ? (S_LEN - 1 - t) : t;
    const float* Arow = X + ((size_t)bb * S_LEN + t_eff) * HID;

    f32x4 acc[2][2];
    #pragma unroll
    for (int i = 0; i < 2; ++i)
        #pragma unroll
        for (int j = 0; j < 2; ++j) { acc[i][j][0]=0.f; acc[i][j][1]=0.f; acc[i][j][2]=0.f; acc[i][j][3]=0.f; }

    for (int kb = 0; kb < HID / 32; ++kb) {
        {
            const float* p = Arow + kb * 32 + ak;
            float4 v0 = *(const float4*)p;
            float4 v1 = *(const float4*)(p + 4);
            FragU fu;
            fu.u[0]=f2bf(v0.x); fu.u[1]=f2bf(v0.y); fu.u[2]=f2bf(v0.z); fu.u[3]=f2bf(v0.w);
            fu.u[4]=f2bf(v1.x); fu.u[5]=f2bf(v1.y); fu.u[6]=f2bf(v1.z); fu.u[7]=f2bf(v1.w);
            *(uint4*)&As[ai][ak] = fu.q;
        }
        {
            const float* p = Wi + (size_t)(kb * 32 + bk) * GATE4 + n0 + bj;
            float4 v0 = *(const float4*)p;
            float4 v1 = *(const float4*)(p + 4);
            unsigned short tmp[8] = { f2bf(v0.x), f2bf(v0.y), f2bf(v0.z), f2bf(v0.w),
                                      f2bf(v1.x), f2bf(v1.y), f2bf(v1.z), f2bf(v1.w) };
            #pragma unroll
            for (int jj = 0; jj < 8; ++jj) Bs[bj + jj][bk] = tmp[jj];
        }
        __syncthreads();

        bf16x8 a0 = *(const bf16x8*)&As[wm * 32 + l16][quad * 8];
        bf16x8 a1 = *(const bf16x8*)&As[wm * 32 + 16 + l16][quad * 8];
        bf16x8 B0 = *(const bf16x8*)&Bs[wn * 32 + l16][quad * 8];
        bf16x8 B1 = *(const bf16x8*)&Bs[wn * 32 + 16 + l16][quad * 8];
        acc[0][0] = __builtin_amdgcn_mfma_f32_16x16x32_bf16(a0, B0, acc[0][0], 0, 0, 0);
        acc[0][1] = __builtin_amdgcn_mfma_f32_16x16x32_bf16(a0, B1, acc[0][1], 0, 0, 0);
        acc[1][0] = __builtin_amdgcn_mfma_f32_16x16x32_bf16(a1, B0, acc[1][0], 0, 0, 0);
        acc[1][1] = __builtin_amdgcn_mfma_f32_16x16x32_bf16(a1, B1, acc[1][1], 0, 0, 0);
        __syncthreads();
    }

    #pragma unroll
    for (int am = 0; am < 2; ++am)
        #pragma unroll
        for (int bn = 0; bn < 2; ++bn) {
            int ncol = n0 + wn * 32 + bn * 16 + l16;
            float bv = bias[ncol];
            #pragma unroll
            for (int rr = 0; rr < 4; ++rr) {
                int rrow = r0 + wm * 32 + am * 16 + quad * 4 + rr;
                float v = acc[am][bn][rr] + bv;
                xp[(size_t)rrow * GATE4 + ncol] = f2bf(v);
            }
        }
}

// ---------------------------------------------------------------------------
// Kernel 2: recurrence. 64 WGs; election (proven r3) picks 4 co-XCD WGs with
// roles (dir, half). Exchange = TAGGED 8B words: {2xbf16 data | step tag}
// stored/loaded with relaxed agent-scope atomics (the exact primitives proven
// in r3 — no inline-asm cache ops). Data is its own flag -> ONE coherence
// round trip per step instead of r3's three (ack, flag, data). Parity
// double-buffer makes slot overwrite provably safe (a WG publishes s+2 only
// after observing partner's s+1, which implies partner consumed s). hbuf
// double-buffered -> ONE barrier per step (r3 had three).
// ---------------------------------------------------------------------------
__global__ __launch_bounds__(512, 2) void lstm_rec(
    const float* __restrict__ Wh_fw, const float* __restrict__ Wh_rv,
    const unsigned short* __restrict__ xp_fw, const unsigned short* __restrict__ xp_rv,
    float* __restrict__ out,            // [B][S][512]
    float* __restrict__ finals,         // c_fw,h_fw,c_rv,h_rv (each 16x256)
    char* __restrict__ exch,            // [dir][parity][half][512 threads][16B]
    unsigned int* __restrict__ ctrl)
{
    const int tid  = threadIdx.x;
    __shared__ int role_s;

    // ---- XCD claim: elect 4 co-XCD workgroups (RMW spin: always coherent) --
    if (tid == 0) {
        unsigned xcc;
        asm volatile("s_getreg_b32 %0, hwreg(HW_REG_XCC_ID)" : "=s"(xcc));
        xcc &= 7u;
        int role = -1;
        unsigned idx = atomicAdd(&ctrl[8u + xcc], 1u);
        if (idx < 4u) {
            if (idx == 3u) atomicCAS(&ctrl[16], 0xFFFFFFFFu, xcc);
            unsigned w;
            while ((w = __hip_atomic_fetch_add(&ctrl[16], 0u, __ATOMIC_RELAXED,
                                               __HIP_MEMORY_SCOPE_AGENT)) == 0xFFFFFFFFu)
                __builtin_amdgcn_s_sleep(2);
            if (w == xcc) role = (int)idx;
        }
        role_s = role;
    }
    __syncthreads();
    const int role = role_s;
    if (role < 0) return;               // uniform per WG

    const int dir  = role >> 1;
    const int half = role & 1;
    const float* Wh = dir ? Wh_rv : Wh_fw;
    const unsigned short* xp = dir ? xp_rv : xp_fw;

    const int lane = tid & 63;
    const int wid  = tid >> 6;          // 0..7
    const int quad = lane >> 4;
    const int l16  = lane & 15;

    const int fbase = half * 128 + wid * 16;   // dir-local f of this wave
    const int floc  = wid * 16 + l16;          // half-local f (0..127)
    const int po    = (1 - half) * 128;        // partner's column base in hbuf

    __shared__ unsigned short hbuf[2][16][264]; // double-buffered full h (bf16)

    for (int i = tid; i < 2 * 16 * 264; i += 512) (&hbuf[0][0][0])[i] = 0;

    // Wh half -> B-fragments (one-time). lane: Wh[kt*32+quad*8+j][g*256+fbase+l16]
    bf16x8 Bfrag[4][8];
    #pragma unroll
    for (int g = 0; g < 4; ++g) {
        int col = g * 256 + fbase + l16;
        #pragma unroll
        for (int kt = 0; kt < 8; ++kt) {
            FragU fu;
            #pragma unroll
            for (int j = 0; j < 8; ++j) {
                int k = kt * 32 + quad * 8 + j;
                fu.u[j] = f2bf(Wh[(size_t)k * GATE4 + col]);
            }
            Bfrag[g][kt] = fu.v;
        }
    }

    float cst[4]  = {0.f, 0.f, 0.f, 0.f};
    float hval[4] = {0.f, 0.f, 0.f, 0.f};

    const size_t lanebase = (size_t)(quad * 4) * GATE4 + fbase + l16;

    // exch slot bases: 8 KiB per (dir,parity,half) block, 16 B per thread
    unsigned long long* exA = (unsigned long long*)(exch
        + (size_t)(((dir * 2 + 0) * 2) + half) * 8192) + (size_t)tid * 2;
    unsigned long long* exB = (unsigned long long*)(exch
        + (size_t)(((dir * 2 + 1) * 2) + half) * 8192) + (size_t)tid * 2;
    const unsigned long long* pdA = (const unsigned long long*)(exch
        + (size_t)(((dir * 2 + 0) * 2) + (1 - half)) * 8192) + (size_t)tid * 2;
    const unsigned long long* pdB = (const unsigned long long*)(exch
        + (size_t)(((dir * 2 + 1) * 2) + (1 - half)) * 8192) + (size_t)tid * 2;

    // xp register sets (even/odd step), refetched 2 ahead
    unsigned short xpA[4][4], xpB[4][4];
    {
        const unsigned short* x0 = xp + lanebase;
        const unsigned short* x1 = xp + (size_t)BATCH * GATE4 + lanebase;
        #pragma unroll
        for (int g = 0; g < 4; ++g)
            #pragma unroll
            for (int rr = 0; rr < 4; ++rr) {
                xpA[g][rr] = x0[(size_t)rr * GATE4 + g * 256];
                xpB[g][rr] = x1[(size_t)rr * GATE4 + g * 256];
            }
    }

    __syncthreads();   // hbuf zeroed

    auto step = [&](int s, unsigned short (&xpc)[4][4],
                    unsigned long long* exm, const unsigned long long* pdm) {
        const int p = s & 1;
        const bool last = (s == S_LEN - 1);

        // 1. A-fragments from full h (buffer p; this step's writes go to p^1)
        bf16x8 Afrag[8];
        #pragma unroll
        for (int kt = 0; kt < 8; ++kt)
            Afrag[kt] = *(const bf16x8*)&hbuf[p][l16][kt * 32 + quad * 8];

        // 2. MFMA
        f32x4 accg[4];
        #pragma unroll
        for (int g = 0; g < 4; ++g) { accg[g][0]=0.f; accg[g][1]=0.f; accg[g][2]=0.f; accg[g][3]=0.f; }
        #pragma unroll
        for (int kt = 0; kt < 8; ++kt) {
            accg[0] = __builtin_amdgcn_mfma_f32_16x16x32_bf16(Afrag[kt], Bfrag[0][kt], accg[0], 0, 0, 0);
            accg[1] = __builtin_amdgcn_mfma_f32_16x16x32_bf16(Afrag[kt], Bfrag[1][kt], accg[1], 0, 0, 0);
            accg[2] = __builtin_amdgcn_mfma_f32_16x16x32_bf16(Afrag[kt], Bfrag[2][kt], accg[2], 0, 0, 0);
            accg[3] = __builtin_amdgcn_mfma_f32_16x16x32_bf16(Afrag[kt], Bfrag[3][kt], accg[3], 0, 0, 0);
        }

        // 3. gates
        unsigned short hb[4];
        #pragma unroll
        for (int rr = 0; rr < 4; ++rr) {
            float zi = accg[0][rr] + bf2f(xpc[0][rr]);
            float zf = accg[1][rr] + bf2f(xpc[1][rr]);
            float zg = accg[2][rr] + bf2f(xpc[2][rr]);
            float zo = accg[3][rr] + bf2f(xpc[3][rr]);
            float ig = sigmoid_f(zi);
            float fg = sigmoid_f(zf);
            float gg = tanh_f(zg);
            float og = sigmoid_f(zo);
            float c  = fg * cst[rr] + ig * gg;
            cst[rr]  = c;
            float h  = og * tanh_f(c);
            hval[rr] = h;
            hb[rr]   = f2bf(h);
        }

        if (!last) {
            // 4. publish own half: two tagged 8B relaxed agent atomics
            //    (fire-and-forget; data is its own flag)
            const unsigned long long tag = (unsigned long long)(unsigned)(s + 1) << 32;
            unsigned long long w0 = tag | (unsigned)hb[0] | ((unsigned)hb[1] << 16);
            unsigned long long w1 = tag | (unsigned)hb[2] | ((unsigned)hb[3] << 16);
            __hip_atomic_store(exm,     w0, __ATOMIC_RELAXED, __HIP_MEMORY_SCOPE_AGENT);
            __hip_atomic_store(exm + 1, w1, __ATOMIC_RELAXED, __HIP_MEMORY_SCOPE_AGENT);
        }

        // 5. own half -> hbuf[p^1]
        #pragma unroll
        for (int rr = 0; rr < 4; ++rr)
            hbuf[p ^ 1][quad * 4 + rr][fbase + l16] = hb[rr];

        if (!last) {
            // 6. poll partner's tagged words (each thread its own 16B; no
            //    contention hot-spot; one visibility latency on the path)
            const unsigned tag = (unsigned)(s + 1);
            unsigned long long w0, w1;
            do {
                w0 = __hip_atomic_load(pdm,     __ATOMIC_RELAXED, __HIP_MEMORY_SCOPE_AGENT);
                w1 = __hip_atomic_load(pdm + 1, __ATOMIC_RELAXED, __HIP_MEMORY_SCOPE_AGENT);
            } while ((unsigned)(w0 >> 32) != tag || (unsigned)(w1 >> 32) != tag);

            // 7. partner half -> hbuf[p^1]
            hbuf[p ^ 1][quad * 4 + 0][po + floc] = (unsigned short)(w0);
            hbuf[p ^ 1][quad * 4 + 1][po + floc] = (unsigned short)(w0 >> 16);
            hbuf[p ^ 1][quad * 4 + 2][po + floc] = (unsigned short)(w1);
            hbuf[p ^ 1][quad * 4 + 3][po + floc] = (unsigned short)(w1 >> 16);
        }

        // 8. out stores (fire & forget; stay in flight across the barrier)
        {
            int t_orig = dir ? (S_LEN - 1 - s) : s;
            float* ob = out + (size_t)t_orig * 512 + dir * 256 + fbase + l16;
            #pragma unroll
            for (int rr = 0; rr < 4; ++rr)
                ob[(size_t)(quad * 4 + rr) * S_LEN * 512] = hval[rr];
        }
        // 9. xp refetch 2 ahead (drained by next step's poll loop)
        if (s + 2 < S_LEN) {
            const unsigned short* xr = xp + (size_t)(s + 2) * (BATCH * GATE4) + lanebase;
            #pragma unroll
            for (int g = 0; g < 4; ++g)
                #pragma unroll
                for (int rr = 0; rr < 4; ++rr)
                    xpc[g][rr] = xr[(size_t)rr * GATE4 + g * 256];
        }

        if (!last) {
            // 10. ONE barrier per step: LDS writes visible to all waves;
            //     global loads/stores stay in flight (lgkmcnt only).
            asm volatile("s_waitcnt lgkmcnt(0)" ::: "memory");
            __builtin_amdgcn_s_barrier();
        }
    };

    for (int s2 = 0; s2 < S_LEN; s2 += 2) {
        step(s2,     xpA, exA, pdA);
        step(s2 + 1, xpB, exB, pdB);
    }

    // final states: c then h, fw block then rv block
    {
        float* cdst = finals + (dir ? 8192 : 0);
        float* hdst = cdst + 4096;
        #pragma unroll
        for (int rr = 0; rr < 4; ++rr) {
            int m = quad * 4 + rr;
            int f = fbase + l16;
            cdst[m * 256 + f] = cst[rr];
            hdst[m * 256 + f] = hval[rr];
        }
    }
}

// ---------------------------------------------------------------------------
extern "C" void kernel_launch(void* const* d_in, const int* in_sizes, int n_in,
                              void* d_out, int out_size, void* d_ws, size_t ws_size,
                              hipStream_t stream)
{
    const float* X     = (const float*)d_in[0];
    const float* Wi_fw = (const float*)d_in[1];
    const float* Wh_fw = (const float*)d_in[2];
    const float* b_fw  = (const float*)d_in[3];
    const float* Wi_rv = (const float*)d_in[4];
    const float* Wh_rv = (const float*)d_in[5];
    const float* b_rv  = (const float*)d_in[6];

    float* out    = (float*)d_out;
    float* finals = out + (size_t)BATCH * S_LEN * 512;

    char* ws = (char*)d_ws;
    unsigned short* xp_fw = (unsigned short*)ws;                          // 128 MiB
    unsigned short* xp_rv = (unsigned short*)(ws + 134217728ull);         // 128 MiB
    char*           exch  = ws + 268435456ull;                            // 64 KiB
    unsigned int*   ctrl  = (unsigned int*)(ws + 268435456ull + 65536ull);// 512 B

    init_ctrl<<<1, 1024, 0, stream>>>(ctrl, (unsigned int*)exch);

    dim3 g(65536 / 64, 1024 / 64, 2);
    xp_gemm<<<g, 256, 0, stream>>>(X, Wi_fw, b_fw, Wi_rv, b_rv, xp_fw, xp_rv);

    lstm_rec<<<64, 512, 0, stream>>>(Wh_fw, Wh_rv, xp_fw, xp_rv, out, finals, exch, ctrl);
}